// Round 7
// baseline (154.161 us; speedup 1.0000x reference)
//
#include <hip/hip_runtime.h>

// ---------------------------------------------------------------------------
// SgpiSTFT: Hermitian iFFT (as GEMM vs fixed cos/sin matrix) + window + 4-tap
// overlap-add + flip/transpose, fused.
//
//   y[n,t] = Re(c0) + 2*sum_{k=1..255}( Re_k cos(2pi n k/512) + Im_k sin(...) )
//   out[b, t*256 + (255-j)] = 256*( y[256+j,t]  *win[768+j]
//                                  + y[j,  t-1] *win[512+j]
//                                  + y[256+j,t-2]*win[256+j]
//                                  + y[j,  t-3] *win[j] )
// Symmetry: y[256+j] flips sign of odd-k terms -> accumulate even-k (E) and
// odd-k (O) halves; Y=E+O, Yh=E-O.
//
// Round-6 (resubmit, broker timeout): cross-tile pipeline (T14 issue-early).
// R3/R5 post-mortem: 44us invariant across 2x-4x occupancy and 2x LDS volume
// -> limiter is the serial stage->barrier->MFMA->store phase chain (no pipe
// >30% busy, traffic ideal). This round: persistent blocks, grid=256 (1/CU),
// 512 thr / 8 waves (R3's validated 2-j-tile/wave layout). Block handles
// tiles {bid>>3,+32,+64} of batch b=bid&7. Per tile: ISSUE next tile's
// global loads into regs FIRST, then MFMA main loop + OLA epilogue of current
// tile (loads land under compute), then barrier -> convert+LDS-write ->
// barrier. win[] hoisted.
// ---------------------------------------------------------------------------

typedef __attribute__((ext_vector_type(8))) short short8;
typedef __attribute__((ext_vector_type(8))) __bf16 bf16x8;
typedef __attribute__((ext_vector_type(4))) float floatx4;

__device__ inline short f2bf(float f) {
  unsigned u = __builtin_bit_cast(unsigned, f);
  u = (u + 0x7fffu + ((u >> 16) & 1u)) >> 16;
  return (short)(unsigned short)u;
}

#define PI_OVER_256 0.01227184630308513f

// M matrix in MFMA fragment order (validated R3/R5):
//   frag idx = (Jtile*16 + s)*64 + lane ; lane holds row j = Jtile*16+(lane&15),
//   kappa = s*32 + (lane>>4)*8 + e, e=0..7 (one short8 per lane).
//   kappa < 256: gk = 2*kappa (even);  kappa >= 256: gk = 2*(kappa-256)+1 (odd)
//   M[j][gk] = (gk==0) ? 1 : (gk<256 ? 2cos(2pi j gk/512) : 2sin(2pi j (gk-256)/512))
__global__ void build_m(short* __restrict__ M) {
  int idx = blockIdx.x * blockDim.x + threadIdx.x;  // [0, 16*16*64)
  int ntile = idx >> 10;
  int s = (idx >> 6) & 15;
  int lane = idx & 63;
  int n = ntile * 16 + (lane & 15);
  int kb = lane >> 4;
  short8 v;
#pragma unroll
  for (int e = 0; e < 8; e++) {
    int kap = s * 32 + kb * 8 + e;
    int gk = 2 * (kap & 255) + (kap >> 8);
    float val;
    if (gk == 0) {
      val = 1.0f;
    } else if (gk < 256) {
      int m = (n * gk) & 511;
      val = 2.0f * __cosf((float)m * PI_OVER_256);
    } else {
      int m = (n * (gk - 256)) & 511;
      val = 2.0f * __sinf((float)m * PI_OVER_256);
    }
    v[e] = f2bf(val);
  }
  ((short8*)M)[idx] = v;
}

// Persistent block: batch b = bid&7, tiles {bid>>3, +32, +64 (<67)}.
// Tile: X columns [c0, c0+64), c0 = 60*tile - 4 (halo 4, 16B-aligned loads).
// Outputs local L in [4,64) -> t = c0+L, masked to t <= 3998.
// 512 threads = 8 waves; wave w owns j-tiles {2w, 2w+1} for all 64 t-cols.
__global__ __launch_bounds__(512, 2) void gemm_ola(
    const float* __restrict__ in, const float* __restrict__ win,
    const short* __restrict__ M, float* __restrict__ out) {
  // X tile, bf16, column-major [col][kappa], kappa groups of 8 XOR-swizzled by
  // (col&7) -> conflict-tolerable b128 reads/writes. Single buffer; the next
  // tile's data is carried in registers (f[2][8]) while this one is computed.
  __shared__ short ldsX[64 * 512];  // 64 KiB

  const int tid = threadIdx.x;
  const int bid = blockIdx.x;      // [0, 256)
  const int b = bid & 7;
  const int t0 = bid >> 3;         // [0, 32)

  // staging geometry (fixed per thread): 4 cols x 8 kappa x 2 passes
  const int cbase = 4 * (tid & 15);  // 16 col-groups
  const int kg = tid >> 4;           // kappa-group 0..31 (8 kappa each)
  const float* srcb = in + (size_t)b * 2056000;

  const int w = tid >> 6;
  const int lane = tid & 63;
  const int c = lane & 15;   // MFMA spatial index within 16-tile
  const int rg = lane >> 4;  // k-block; also C row-group
  const short8* Mf = (const short8*)M;
  const int J0 = 2 * w, J1 = 2 * w + 1;

  // hoisted window weights (per jt)
  float wv[2][4];
#pragma unroll
  for (int jt = 0; jt < 2; jt++) {
    const int j = 16 * (2 * w + jt) + c;
    wv[jt][0] = 256.0f * win[768 + j];
    wv[jt][1] = 256.0f * win[512 + j];
    wv[jt][2] = 256.0f * win[256 + j];
    wv[jt][3] = 256.0f * win[j];
  }

  floatx4 f[2][8];  // register-staged tile (carried across main loop)

  auto load_f = [&](int tile_) {
    const int gc = 60 * tile_ - 4 + cbase;
    if (gc >= 0 && gc <= 3996) {
      const float* src = srcb + gc;
#pragma unroll
      for (int p = 0; p < 2; p++)
#pragma unroll
        for (int j = 0; j < 8; j++) {
          const int kk = kg * 8 + j;          // kap & 255
          const int gk = 2 * kk + p;          // kap>>8 == p
          const int row = (gk < 256) ? gk : gk + 1;  // imag rows start at 257
          f[p][j] = *(const floatx4*)(src + (size_t)row * 4000);
        }
    } else {
#pragma unroll
      for (int p = 0; p < 2; p++)
#pragma unroll
        for (int j = 0; j < 8; j++) f[p][j] = floatx4{0.f, 0.f, 0.f, 0.f};
    }
  };

  auto write_lds = [&]() {
#pragma unroll
    for (int p = 0; p < 2; p++) {
      const int g = kg + 32 * p;  // kappa-group, 8-aligned
#pragma unroll
      for (int cc = 0; cc < 4; cc++) {
        short8 v;
#pragma unroll
        for (int j = 0; j < 8; j++) v[j] = f2bf(f[p][j][cc]);
        const int col = cbase + cc;
        *(short8*)&ldsX[col * 512 + ((g ^ (col & 7)) << 3)] = v;
      }
    }
  };

  // ---- prologue: stage first tile ----
  load_f(t0);
  write_lds();
  __syncthreads();

  for (int tile = t0; tile < 67; tile += 32) {
    const int c0 = 60 * tile - 4;
    const bool have_next = (tile + 32) < 67;

    // T14 issue-early: launch next tile's global loads now; they land under
    // the main loop + epilogue below, consumed by write_lds at the bottom.
    if (have_next) load_f(tile + 32);

    // ---- main loop: acc[q][jt], q = t-tile (4 x 16 cols), jt = j-tile ----
    floatx4 accE[4][2] = {};
    floatx4 accO[4][2] = {};

    bf16x8 cb0 = __builtin_bit_cast(bf16x8, Mf[(J0 * 16 + 0) * 64 + lane]);
    bf16x8 cb1 = __builtin_bit_cast(bf16x8, Mf[(J1 * 16 + 0) * 64 + lane]);

#pragma unroll
    for (int s = 0; s < 16; s++) {
      bf16x8 nb0, nb1;
      if (s < 15) {
        nb0 = __builtin_bit_cast(bf16x8, Mf[(J0 * 16 + s + 1) * 64 + lane]);
        nb1 = __builtin_bit_cast(bf16x8, Mf[(J1 * 16 + s + 1) * 64 + lane]);
      }
      // A fragments (X) from LDS: lane m = t-col; (16q+c)&7 == c&7.
      const int g = 4 * s + rg;
      bf16x8 a[4];
#pragma unroll
      for (int q = 0; q < 4; q++) {
        const int col = 16 * q + c;
        a[q] = __builtin_bit_cast(
            bf16x8, *(const short8*)&ldsX[col * 512 + ((g ^ (c & 7)) << 3)]);
      }
      if (s < 8) {
#pragma unroll
        for (int q = 0; q < 4; q++) {
          accE[q][0] = __builtin_amdgcn_mfma_f32_16x16x32_bf16(a[q], cb0, accE[q][0], 0, 0, 0);
          accE[q][1] = __builtin_amdgcn_mfma_f32_16x16x32_bf16(a[q], cb1, accE[q][1], 0, 0, 0);
        }
      } else {
#pragma unroll
        for (int q = 0; q < 4; q++) {
          accO[q][0] = __builtin_amdgcn_mfma_f32_16x16x32_bf16(a[q], cb0, accO[q][0], 0, 0, 0);
          accO[q][1] = __builtin_amdgcn_mfma_f32_16x16x32_bf16(a[q], cb1, accO[q][1], 0, 0, 0);
        }
      }
      if (s < 15) { cb0 = nb0; cb1 = nb1; }
    }

    // ---- OLA epilogue (no LDS use; overlaps next-tile loads in flight) ----
    // C layout: col (lane&15) = j within j-tile; row (rg*4+p) = local t offs.
    // Tap t-d = reg p-d; p-d<0 pulls reg p-d+4 from the row-group below
    // (lane-16, same q-tile) or, for rg==0, from rg=3 of tile q-1 (lane+48).
    // q==0 && rg==0 edge rows are L<4 -> masked.
#pragma unroll
    for (int jt = 0; jt < 2; jt++) {
      const int j = 16 * (2 * w + jt) + c;

      floatx4 Y[4], Yh[4];
#pragma unroll
      for (int q = 0; q < 4; q++) {
        Y[q] = accE[q][jt] + accO[q][jt];
        Yh[q] = accE[q][jt] - accO[q][jt];
      }

#pragma unroll
      for (int q = 0; q < 4; q++) {
        const int qm = (q > 0) ? q - 1 : 0;  // q==0 edge is masked (L<4)
        float yb[4], yhb[4];
#pragma unroll
        for (int p = 1; p < 4; p++) {
          float ia = __shfl(Y[q][p], lane - 16, 64);
          float pa = __shfl(Y[qm][p], lane + 48, 64);
          yb[p] = (rg > 0) ? ia : pa;
        }
#pragma unroll
        for (int p = 2; p < 4; p++) {
          float ia = __shfl(Yh[q][p], lane - 16, 64);
          float pa = __shfl(Yh[qm][p], lane + 48, 64);
          yhb[p] = (rg > 0) ? ia : pa;
        }
        floatx4 v;
#pragma unroll
        for (int p = 0; p < 4; p++) {
          float t1 = (p >= 1) ? Y[q][p - 1] : yb[3];
          float t2 = (p >= 2) ? Yh[q][p - 2] : yhb[p + 2];
          float t3 = (p >= 3) ? Y[q][p - 3] : yb[p + 1];
          v[p] = wv[jt][0] * Yh[q][p] + wv[jt][1] * t1 + wv[jt][2] * t2 +
                 wv[jt][3] * t3;
        }
#pragma unroll
        for (int p = 0; p < 4; p++) {
          const int L = 16 * q + 4 * rg + p;
          const int t = c0 + L;
          if (L >= 4 && t <= 3998) {
            out[((size_t)b * 3999 + t) * 256 + (255 - j)] = v[p];
          }
        }
      }
    }

    // ---- rotate: publish next tile into LDS ----
    if (have_next) {
      __syncthreads();   // all waves done reading current LDS tile
      write_lds();       // waits on the early-issued loads (vmcnt) here
      __syncthreads();
    }
  }
}

extern "C" void kernel_launch(void* const* d_in, const int* in_sizes, int n_in,
                              void* d_out, int out_size, void* d_ws, size_t ws_size,
                              hipStream_t stream) {
  const float* in = (const float*)d_in[0];   // (8, 514, 4000) fp32
  const float* win = (const float*)d_in[1];  // (1024,) fp32
  float* out = (float*)d_out;                // (8, 3999*256) fp32
  short* M = (short*)d_ws;                   // 256 KiB bf16 coefficient matrix

  hipLaunchKernelGGL(build_m, dim3(64), dim3(256), 0, stream, M);
  hipLaunchKernelGGL(gemm_ola, dim3(256), dim3(512), 0, stream, in, win, M, out);
}

// Round 9
// 117.811 us; speedup vs baseline: 1.3085x; 1.3085x over previous
//
#include <hip/hip_runtime.h>

// ---------------------------------------------------------------------------
// SgpiSTFT: Hermitian iFFT (as GEMM vs fixed cos/sin matrix) + window + 4-tap
// overlap-add + flip/transpose, fused.
//
//   y[n,t] = Re(c0) + 2*sum_{k=1..255}( Re_k cos(2pi n k/512) + Im_k sin(...) )
//   out[b, t*256 + (255-j)] = 256*( y[256+j,t]  *win[768+j]
//                                  + y[j,  t-1] *win[512+j]
//                                  + y[256+j,t-2]*win[256+j]
//                                  + y[j,  t-3] *win[j] )
// Symmetry: y[256+j] flips sign of odd-k terms -> accumulate even-k (E) and
// odd-k (O) halves; Y=E+O, Yh=E-O.
//
// Round-8 (resubmit, broker timeout): K-chunked staging pipeline. R6
// post-mortem: 64-VGPR tile carry -> scratch spills (+75MB HBM traffic,
// 73us). R3/R5 post-mortem: 44us = SUM of serialized phases (HBM 13 + LDS 12
// + MFMA 4.5 + epilogue ~8), no pipe >30%. This round keeps R5's validated
// frame (1024 thr / 16 waves / 64-col tile / grid 67x8 / M layout / epilogue)
// and overlaps staging with compute at 128-kappa chunk granularity: issue
// chunk ch+1's 8 scalar loads -> compute 4 s-steps on chunk ch -> convert+
// ds_write ch+1 -> barrier. In-flight state is 8 floats/thread (no spill).
// Disjoint LDS regions per chunk -> race-free single buffer; no loads in
// flight at barriers (no drain penalty).
// ---------------------------------------------------------------------------

typedef __attribute__((ext_vector_type(8))) short short8;
typedef __attribute__((ext_vector_type(8))) __bf16 bf16x8;
typedef __attribute__((ext_vector_type(4))) float floatx4;

__device__ inline short f2bf(float f) {
  unsigned u = __builtin_bit_cast(unsigned, f);
  u = (u + 0x7fffu + ((u >> 16) & 1u)) >> 16;
  return (short)(unsigned short)u;
}

#define PI_OVER_256 0.01227184630308513f

// M matrix in MFMA fragment order (validated R3/R5):
//   frag idx = (Jtile*16 + s)*64 + lane ; lane holds row j = Jtile*16+(lane&15),
//   kappa = s*32 + (lane>>4)*8 + e, e=0..7 (one short8 per lane).
//   kappa < 256: gk = 2*kappa (even);  kappa >= 256: gk = 2*(kappa-256)+1 (odd)
//   M[j][gk] = (gk==0) ? 1 : (gk<256 ? 2cos(2pi j gk/512) : 2sin(2pi j (gk-256)/512))
__global__ void build_m(short* __restrict__ M) {
  int idx = blockIdx.x * blockDim.x + threadIdx.x;  // [0, 16*16*64)
  int ntile = idx >> 10;
  int s = (idx >> 6) & 15;
  int lane = idx & 63;
  int n = ntile * 16 + (lane & 15);
  int kb = lane >> 4;
  short8 v;
#pragma unroll
  for (int e = 0; e < 8; e++) {
    int kap = s * 32 + kb * 8 + e;
    int gk = 2 * (kap & 255) + (kap >> 8);
    float val;
    if (gk == 0) {
      val = 1.0f;
    } else if (gk < 256) {
      int m = (n * gk) & 511;
      val = 2.0f * __cosf((float)m * PI_OVER_256);
    } else {
      int m = (n * (gk - 256)) & 511;
      val = 2.0f * __sinf((float)m * PI_OVER_256);
    }
    v[e] = f2bf(val);
  }
  ((short8*)M)[idx] = v;
}

// Block: batch b, X columns [c0, c0+64), c0 = 60*tile - 4 (halo 4). Outputs
// local L in [4,64) -> t = c0+L, masked to t <= 3998. 1024 threads = 16
// waves; wave w owns j-tile J=w (j rows 16w..16w+15) for all 64 t-columns.
// Staging: per chunk ch (128 kappa), thread loads col=tid&63, kappa
// ch*128+(tid>>6)*8 .. +7 as 8 coalesced scalar dwords -> short8 -> one
// ds_write_b128 into the same XOR-swizzled layout as R5.
__global__ __launch_bounds__(1024, 4) void gemm_ola(
    const float* __restrict__ in, const float* __restrict__ win,
    const short* __restrict__ M, float* __restrict__ out) {
  // X tile, bf16, column-major [col][kappa], kappa groups of 8 XOR-swizzled
  // by (col&7) -> conflict-tolerable b128 reads/writes.
  __shared__ short ldsX[64 * 512];  // 64 KiB

  const int tid = threadIdx.x;
  const int b = blockIdx.y;
  const int tile = blockIdx.x;
  const int c0 = 60 * tile - 4;

  // staging geometry (fixed per thread)
  const int scol = tid & 63;   // column within tile
  const int skg = tid >> 6;    // kappa-group-of-8 within chunk, 0..15
  const int sgc = c0 + scol;
  const bool sok = (sgc >= 0 && sgc <= 3999);
  const float* src = in + (size_t)b * 2056000 + sgc;

  const int w = tid >> 6;    // wave id == j-tile J (== skg, both tid>>6)
  const int lane = tid & 63;
  const int c = lane & 15;   // MFMA spatial index within 16-tile
  const int rg = lane >> 4;  // k-block; also C row-group
  const short8* Mf = (const short8*)M;

  float fst[8];  // in-flight staging chunk (8 floats/thread)

#define ISSUE_LOADS(CH)                                              \
  {                                                                  \
    _Pragma("unroll") for (int e = 0; e < 8; e++) {                  \
      const int kap = (CH) * 128 + skg * 8 + e;                      \
      const int gk = 2 * (kap & 255) + (kap >> 8);                   \
      const int row = (gk < 256) ? gk : gk + 1;                      \
      fst[e] = sok ? src[(size_t)row * 4000] : 0.f;                  \
    }                                                                \
  }

#define WRITE_CHUNK(CH)                                              \
  {                                                                  \
    short8 v;                                                        \
    _Pragma("unroll") for (int e = 0; e < 8; e++) v[e] = f2bf(fst[e]); \
    const int g = (CH) * 16 + skg;                                   \
    *(short8*)&ldsX[scol * 512 + ((g ^ (scol & 7)) << 3)] = v;       \
  }

  // ---- prologue: stage chunk 0 ----
  ISSUE_LOADS(0);
  WRITE_CHUNK(0);
  __syncthreads();

  // acc[q]: q = t-tile (4 tiles = 64 cols); E = even-k, O = odd-k
  floatx4 accE[4] = {};
  floatx4 accO[4] = {};

  bf16x8 cb = __builtin_bit_cast(bf16x8, Mf[(w * 16 + 0) * 64 + lane]);

#pragma unroll
  for (int ch = 0; ch < 4; ch++) {
    // issue next chunk's global loads; they land under the 4 s-steps below
    if (ch < 3) ISSUE_LOADS(ch + 1);

#pragma unroll
    for (int si = 0; si < 4; si++) {
      const int s = 4 * ch + si;
      // prefetch next-s M fragment (L2) before touching this step's MFMAs
      bf16x8 nb;
      if (s < 15) {
        nb = __builtin_bit_cast(bf16x8, Mf[(w * 16 + s + 1) * 64 + lane]);
      }
      // A fragments (X) from LDS: lane m = t-col; (16q+c)&7 == c&7.
      const int g = 4 * s + rg;
      bf16x8 a[4];
#pragma unroll
      for (int q = 0; q < 4; q++) {
        const int col = 16 * q + c;
        a[q] = __builtin_bit_cast(
            bf16x8, *(const short8*)&ldsX[col * 512 + ((g ^ (c & 7)) << 3)]);
      }
      if (s < 8) {
#pragma unroll
        for (int q = 0; q < 4; q++)
          accE[q] = __builtin_amdgcn_mfma_f32_16x16x32_bf16(a[q], cb, accE[q], 0, 0, 0);
      } else {
#pragma unroll
        for (int q = 0; q < 4; q++)
          accO[q] = __builtin_amdgcn_mfma_f32_16x16x32_bf16(a[q], cb, accO[q], 0, 0, 0);
      }
      if (s < 15) cb = nb;
    }

    // publish next chunk: convert (waits vmcnt for fst) + write + barrier.
    // Writes target chunk ch+1's LDS region, disjoint from chunk ch's reads
    // still issuing in other waves -> race-free. No loads in flight at the
    // barrier (next chunk's are issued after it), so the vmcnt(0) drain in
    // __syncthreads costs nothing extra.
    if (ch < 3) {
      WRITE_CHUNK(ch + 1);
      __syncthreads();
    }
  }
#undef ISSUE_LOADS
#undef WRITE_CHUNK

  // ---- OLA epilogue (validated R5) ----
  // C layout: col (lane&15) = j within j-tile; row (rg*4+p) = local t offset.
  // Tap t-d = reg p-d; p-d<0 pulls reg p-d+4 from the row-group below
  // (lane-16, same q-tile) or, for rg==0, from rg=3 of tile q-1 (lane+48).
  // q==0 && rg==0 edge rows are L<4 -> masked.
  {
    const int j = 16 * w + c;
    const float wv0 = 256.0f * win[768 + j];
    const float wv1 = 256.0f * win[512 + j];
    const float wv2 = 256.0f * win[256 + j];
    const float wv3 = 256.0f * win[j];

    floatx4 Y[4], Yh[4];
#pragma unroll
    for (int q = 0; q < 4; q++) {
      Y[q] = accE[q] + accO[q];
      Yh[q] = accE[q] - accO[q];
    }

#pragma unroll
    for (int q = 0; q < 4; q++) {
      const int qm = (q > 0) ? q - 1 : 0;  // q==0 edge is masked (L<4)
      float yb[4], yhb[4];
#pragma unroll
      for (int p = 1; p < 4; p++) {
        float ia = __shfl(Y[q][p], lane - 16, 64);
        float pa = __shfl(Y[qm][p], lane + 48, 64);
        yb[p] = (rg > 0) ? ia : pa;
      }
#pragma unroll
      for (int p = 2; p < 4; p++) {
        float ia = __shfl(Yh[q][p], lane - 16, 64);
        float pa = __shfl(Yh[qm][p], lane + 48, 64);
        yhb[p] = (rg > 0) ? ia : pa;
      }
      floatx4 v;
#pragma unroll
      for (int p = 0; p < 4; p++) {
        float t1 = (p >= 1) ? Y[q][p - 1] : yb[3];
        float t2 = (p >= 2) ? Yh[q][p - 2] : yhb[p + 2];
        float t3 = (p >= 3) ? Y[q][p - 3] : yb[p + 1];
        v[p] = wv0 * Yh[q][p] + wv1 * t1 + wv2 * t2 + wv3 * t3;
      }
#pragma unroll
      for (int p = 0; p < 4; p++) {
        const int L = 16 * q + 4 * rg + p;
        const int t = c0 + L;
        if (L >= 4 && t <= 3998) {
          out[((size_t)b * 3999 + t) * 256 + (255 - j)] = v[p];
        }
      }
    }
  }
}

extern "C" void kernel_launch(void* const* d_in, const int* in_sizes, int n_in,
                              void* d_out, int out_size, void* d_ws, size_t ws_size,
                              hipStream_t stream) {
  const float* in = (const float*)d_in[0];   // (8, 514, 4000) fp32
  const float* win = (const float*)d_in[1];  // (1024,) fp32
  float* out = (float*)d_out;                // (8, 3999*256) fp32
  short* M = (short*)d_ws;                   // 256 KiB bf16 coefficient matrix

  hipLaunchKernelGGL(build_m, dim3(64), dim3(256), 0, stream, M);
  hipLaunchKernelGGL(gemm_ola, dim3(67, 8), dim3(1024), 0, stream, in, win, M, out);
}